// Round 5
// baseline (592.354 us; speedup 1.0000x reference)
//
#include <hip/hip_runtime.h>
#include <hip/hip_bf16.h>
#include <math.h>

#define B_ 8
#define N_ 1024
#define H_ 14
#define DH_ 64
#define D_ 896
#define M_ (B_*N_)        // 8192 rows
#define DQKV_ 2688        // 3*D_

// exp2-domain constants: 2*log2(e), log2(e)*(1 - M0) with M0 = 12
#define TWO_LOG2E_ 2.8853900817779268f
#define BIAS_C_   (-15.869645449778597f)
#define QSCALE_     0.18033688011112043f   // 0.125 * log2(e), folded into Q at GEMM epilogue

typedef __attribute__((ext_vector_type(8))) short bf16x8;
typedef __attribute__((ext_vector_type(4))) short bf16x4;
typedef __attribute__((ext_vector_type(4))) float f32x4;
typedef __attribute__((ext_vector_type(4))) unsigned u32x4;

__device__ __forceinline__ float bf2f(short s){
  unsigned u = ((unsigned)(unsigned short)s) << 16;
  union { unsigned u; float f; } c; c.u = u; return c.f;
}
__device__ __forceinline__ short f2bf(float f){
  union { float f; unsigned u; } c; c.f = f;
  unsigned u = c.u;
  unsigned r = (u + 0x7FFFu + ((u >> 16) & 1u)) >> 16;
  return (short)(unsigned short)r;
}
__device__ __forceinline__ float asf(unsigned u){
  union { unsigned u; float f; } c; c.u = u; return c.f;
}
// pack 2 f32 -> 2 bf16 in one VALU op (RNE -- bit-identical to f2bf above)
__device__ __forceinline__ unsigned cvt_pk_bf16(float lo, float hi){
  unsigned r;
  asm("v_cvt_pk_bf16_f32 %0, %1, %2" : "=v"(r) : "v"(lo), "v"(hi));
  return r;
}

// ---------------- LayerNorm: one block per row, f32 in -> bf16 out ----------------
__global__ __launch_bounds__(256) void ln_kernel(const float* __restrict__ x,
                                                 const float* __restrict__ g,
                                                 const float* __restrict__ bb,
                                                 short* __restrict__ y)
{
  int row = blockIdx.x;
  const float* xr = x + (size_t)row * D_;
  float s = 0.f, s2 = 0.f;
  for (int i = threadIdx.x; i < D_; i += 256){
    float v = xr[i]; s += v; s2 = fmaf(v, v, s2);
  }
  #pragma unroll
  for (int off = 32; off > 0; off >>= 1){
    s  += __shfl_down(s,  off, 64);
    s2 += __shfl_down(s2, off, 64);
  }
  __shared__ float rs_[4], rs2_[4];
  int wv = threadIdx.x >> 6;
  if ((threadIdx.x & 63) == 0){ rs_[wv] = s; rs2_[wv] = s2; }
  __syncthreads();
  float ts  = rs_[0] + rs_[1] + rs_[2] + rs_[3];
  float ts2 = rs2_[0] + rs2_[1] + rs2_[2] + rs2_[3];
  float mu  = ts * (1.f / D_);
  float var = ts2 * (1.f / D_) - mu * mu;
  float rstd = rsqrtf(var + 1e-5f);
  short* yr = y + (size_t)row * D_;
  for (int i = threadIdx.x; i < D_; i += 256){
    yr[i] = f2bf((xr[i] - mu) * rstd * g[i] + bb[i]);
  }
}

// ---------------- Transpose weights: f32 W[k][n] -> bf16 Wt[n][k] ----------------
__global__ __launch_bounds__(256) void transpose_kernel(
    const float* __restrict__ Wq, const float* __restrict__ Wk,
    const float* __restrict__ Wv, const float* __restrict__ Wo,
    short* __restrict__ WqkvT, short* __restrict__ WoT)
{
  __shared__ short t[64][72];
  int z = blockIdx.z;
  const float* W = (z == 0) ? Wq : (z == 1) ? Wk : (z == 2) ? Wv : Wo;
  int kb = blockIdx.x * 64, nb = blockIdx.y * 64;
  int c0 = (threadIdx.x & 7) * 8;
  int r0 = threadIdx.x >> 3;            // 0..31
  #pragma unroll
  for (int rr = 0; rr < 64; rr += 32){
    const float* src = &W[(size_t)(kb + r0 + rr) * D_ + nb + c0];
    float4 a = *(const float4*)src;
    float4 b = *(const float4*)(src + 4);
    short* dstl = &t[r0 + rr][c0];
    dstl[0] = f2bf(a.x); dstl[1] = f2bf(a.y); dstl[2] = f2bf(a.z); dstl[3] = f2bf(a.w);
    dstl[4] = f2bf(b.x); dstl[5] = f2bf(b.y); dstl[6] = f2bf(b.z); dstl[7] = f2bf(b.w);
  }
  __syncthreads();
  short* dst = (z < 3) ? (WqkvT + (size_t)(z * D_) * D_) : WoT;
  #pragma unroll
  for (int rr = 0; rr < 64; rr += 32){
    int n = nb + r0 + rr;
    bf16x8 v;
    #pragma unroll
    for (int j = 0; j < 8; j++) v[j] = t[c0 + j][r0 + rr];
    *(bf16x8*)&dst[(size_t)n * D_ + kb + c0] = v;
  }
}

// ---------------- V transpose: QKV V-part [tok][d] -> VT[(b,h,d)][tok] bf16 ----------
__global__ __launch_bounds__(256) void vt_kernel(const short* __restrict__ QKV,
                                                 short* __restrict__ VT)
{
  __shared__ short tt[64][72];
  int kt = blockIdx.x;                 // token tile 0..15
  int bh = blockIdx.y;                 // 0..111
  int b  = bh / H_, hh = bh - b * H_;
  int r  = threadIdx.x >> 2;           // 0..63
  int c0 = (threadIdx.x & 3) * 16;     // 0,16,32,48
  const short* src = QKV + ((size_t)(b * N_) + kt * 64 + r) * DQKV_ + 2 * D_ + hh * DH_ + c0;
  *(bf16x8*)&tt[r][c0]     = *(const bf16x8*)src;
  *(bf16x8*)&tt[r][c0 + 8] = *(const bf16x8*)(src + 8);
  __syncthreads();
  // write rows d = r, tokens kt*64 + c0 .. c0+15
  short* dst = VT + ((size_t)bh * DH_ + r) * N_ + kt * 64 + c0;
  bf16x8 v0, v1;
  #pragma unroll
  for (int j = 0; j < 8; j++){ v0[j] = tt[c0 + j][r]; v1[j] = tt[c0 + 8 + j][r]; }
  *(bf16x8*)dst       = v0;
  *(bf16x8*)(dst + 8) = v1;
}

// ---------------- Prep: adjT[k][q]; csb[k][q] (PRE=0) OR alignT[b][k][q] (PRE=1) ----
__global__ __launch_bounds__(256) void prep_kernel(
    const float* __restrict__ adj, const float* __restrict__ brg,
    const float* __restrict__ wdir,
    unsigned* __restrict__ csb, short* __restrict__ adjT,
    short* __restrict__ alignT, int do_align)
{
  int kt = blockIdx.x, qt = blockIdx.y;
  __shared__ short tt[64][72];
  __shared__ float cA_[8][64], sA_[8][64];

  if (do_align){
    for (int idx = threadIdx.x; idx < 8 * 64; idx += 256){
      int b = idx >> 6, q = idx & 63;
      float A = wdir[(size_t)b * N_ + qt * 64 + q] * 0.017453292519943295f;
      float s, c; __sincosf(A, &s, &c);
      sA_[b][q] = s; cA_[b][q] = c;
    }
  }

  int r  = threadIdx.x >> 2;          // 0..63
  int c0 = (threadIdx.x & 3) * 16;    // 0..48

  // adj -> tt staging (for adjT transpose)
  {
    int q = qt * 64 + r;
    const float* ap = adj + (size_t)q * N_ + kt * 64 + c0;
    #pragma unroll
    for (int i = 0; i < 16; i += 4){
      float4 av = *(const float4*)(ap + i);
      tt[r][c0 + i]     = f2bf(av.x);
      tt[r][c0 + i + 1] = f2bf(av.y);
      tt[r][c0 + i + 2] = f2bf(av.z);
      tt[r][c0 + i + 3] = f2bf(av.w);
    }
  }
  __syncthreads();   // covers both cA_/sA_ and tt

  int k = kt * 64 + r;
  // bearing trig for this thread's 16 q's
  float cB[16], sB[16];
  {
    const float* bp = brg + (size_t)k * N_ + qt * 64 + c0;
    #pragma unroll
    for (int i = 0; i < 16; i += 4){
      float4 bv = *(const float4*)(bp + i);
      float b4[4] = { bv.x, bv.y, bv.z, bv.w };
      #pragma unroll
      for (int j = 0; j < 4; j++){
        float Br = (b4[j] + 180.f) * 0.017453292519943295f;
        __sincosf(Br, &sB[i + j], &cB[i + j]);
      }
    }
  }

  if (do_align){
    #pragma unroll
    for (int b = 0; b < 8; b++){
      unsigned w8[8];
      #pragma unroll
      for (int p = 0; p < 8; p++){
        int q0i = c0 + 2 * p, q1i = q0i + 1;
        float a0 = fmaf(cA_[b][q0i], cB[2 * p],     sA_[b][q0i] * sB[2 * p]);
        float a1 = fmaf(cA_[b][q1i], cB[2 * p + 1], sA_[b][q1i] * sB[2 * p + 1]);
        w8[p] = cvt_pk_bf16(a0, a1);
      }
      short* dst = alignT + ((size_t)b * N_ + k) * N_ + qt * 64 + c0;
      *(uint4*)dst       = make_uint4(w8[0], w8[1], w8[2], w8[3]);
      *(uint4*)(dst + 8) = make_uint4(w8[4], w8[5], w8[6], w8[7]);
    }
  } else {
    unsigned* cp = csb + (size_t)k * N_ + qt * 64 + c0;
    #pragma unroll
    for (int i = 0; i < 16; i += 4){
      unsigned o[4];
      #pragma unroll
      for (int j = 0; j < 4; j++)
        o[j] = ((unsigned)(unsigned short)f2bf(cB[i + j])) |
               (((unsigned)(unsigned short)f2bf(sB[i + j])) << 16);
      *(uint4*)(cp + i) = make_uint4(o[0], o[1], o[2], o[3]);
    }
  }

  // adjT via LDS transpose
  {
    short* op = adjT + (size_t)k * N_ + qt * 64 + c0;
    bf16x8 v0, v1;
    #pragma unroll
    for (int j = 0; j < 8; j++){ v0[j] = tt[c0 + j][r]; v1[j] = tt[c0 + 8 + j][r]; }
    *(bf16x8*)op = v0;
    *(bf16x8*)(op + 8) = v1;
  }
}

// ---------------- MFMA GEMM: C[M x N] = A[M x K] * Bt[N x K]^T ----------------
__global__ __launch_bounds__(256) void gemm_bt(const short* __restrict__ A,
                                               const short* __restrict__ Bt,
                                               short* __restrict__ C,
                                               float* __restrict__ Cf,
                                               const float* __restrict__ residf,
                                               int N, int rope)
{
  const int K = D_;
  __shared__ short As[128 * 32];
  __shared__ short Bs[128 * 32];
  int tid  = threadIdx.x;
  int wave = tid >> 6;
  int lane = tid & 63;
  int quad = lane >> 4;
  int l16  = lane & 15;
  int wr = wave >> 1, wc = wave & 1;
  int m0 = blockIdx.x * 128;
  int n0 = blockIdx.y * 128;

  f32x4 acc[4][4];
  #pragma unroll
  for (int i = 0; i < 4; i++)
    #pragma unroll
    for (int j = 0; j < 4; j++)
      acc[i][j] = (f32x4){0.f, 0.f, 0.f, 0.f};

  for (int k0 = 0; k0 < K; k0 += 32){
    __syncthreads();
    #pragma unroll
    for (int it = 0; it < 2; ++it){
      int c   = tid + it * 256;
      int row = c >> 2;
      int cc  = c & 3;
      const short* ga = A  + (size_t)(m0 + row) * K + k0 + cc * 8;
      const short* gb = Bt + (size_t)(n0 + row) * K + k0 + cc * 8;
      short* la = As + (size_t)(wave * 64 + it * 256) * 8;
      short* lb = Bs + (size_t)(wave * 64 + it * 256) * 8;
      __builtin_amdgcn_global_load_lds((const __attribute__((address_space(1))) void*)ga,
                                       (__attribute__((address_space(3))) void*)la, 16, 0, 0);
      __builtin_amdgcn_global_load_lds((const __attribute__((address_space(1))) void*)gb,
                                       (__attribute__((address_space(3))) void*)lb, 16, 0, 0);
    }
    __syncthreads();

    bf16x8 af[4], bfr[4];
    #pragma unroll
    for (int i = 0; i < 4; i++)
      af[i] = *(const bf16x8*)(As + (size_t)(wr * 64 + i * 16 + l16) * 32 + quad * 8);
    #pragma unroll
    for (int j = 0; j < 4; j++)
      bfr[j] = *(const bf16x8*)(Bs + (size_t)(wc * 64 + j * 16 + l16) * 32 + quad * 8);
    #pragma unroll
    for (int i = 0; i < 4; i++)
      #pragma unroll
      for (int j = 0; j < 4; j++)
        acc[i][j] = __builtin_amdgcn_mfma_f32_16x16x32_bf16(af[i], bfr[j], acc[i][j], 0, 0, 0);
  }

  if (rope){
    int cb  = n0 + wc * 64;            // head base col (64-aligned)
    int mat = cb / D_;                 // 0=Q, 1=K, 2=V
    if (mat < 2){
      float scale = (mat == 0) ? QSCALE_ : 1.0f;
      float invf0 = exp2f(-0.4152410118609203f * (float)l16);  // 10000^(-l16/32)
      float invf1 = invf0 * 0.01f;                             // 10000^(-(16+l16)/32)
      #pragma unroll
      for (int i = 0; i < 4; i++){
        #pragma unroll
        for (int rr = 0; rr < 4; rr++){
          int r = m0 + wr * 64 + i * 16 + quad * 4 + rr;
          float nseq = (float)(r & (N_ - 1));
          float s0, c0v, s1, c1v;
          __sincosf(nseq * invf0, &s0, &c0v);
          __sincosf(nseq * invf1, &s1, &c1v);
          float x1 = acc[i][0][rr], x2 = acc[i][2][rr];
          acc[i][0][rr] = (x1 * c0v - x2 * s0) * scale;
          acc[i][2][rr] = (x2 * c0v + x1 * s0) * scale;
          x1 = acc[i][1][rr]; x2 = acc[i][3][rr];
          acc[i][1][rr] = (x1 * c1v - x2 * s1) * scale;
          acc[i][3][rr] = (x2 * c1v + x1 * s1) * scale;
        }
      }
    }
  }

  #pragma unroll
  for (int i = 0; i < 4; i++){
    #pragma unroll
    for (int rr = 0; rr < 4; rr++){
      int r = m0 + wr * 64 + i * 16 + quad * 4 + rr;
      size_t rowoff = (size_t)r * N;
      #pragma unroll
      for (int j = 0; j < 4; j++){
        int cidx = n0 + wc * 64 + j * 16 + l16;
        float v = acc[i][j][rr];
        if (Cf){
          Cf[rowoff + cidx] = v + residf[rowoff + cidx];
        } else {
          C[rowoff + cidx] = f2bf(v);
        }
      }
    }
  }
}

// ---------------- MFMA flash attention: BARRIER-FREE, fixed-max softmax, exp2 ----------
// r1-r4 invariant: dur ~150us across VALU-halving, HBM-halving, occupancy changes ->
// the limiter was the 2-barrier/iter staging lockstep. This version removes ALL
// synchronization:
//  * K read directly from global as B-frags (row-contiguous 16B; L2-resident);
//  * V pre-transposed in global (vt_kernel) -> PV B-frags are row-contiguous 16B;
//  * P_s is wave-private (each wave writes/reads only its own 16 rows) -> no barrier.
// Zero s_barrier in the loop; waves fully independent; LDS 9.7KB/block.
template<int PRE>
__global__ __launch_bounds__(256, 4) void attn_kernel(
    const short* __restrict__ QKV,
    const short* __restrict__ VT,       // [(b*H+h)*64 + d][tok] bf16
    const unsigned* __restrict__ csb,   // [k][q] packed (cosB lo16, sinB hi16)  (PRE=0)
    const short* __restrict__ adjT,     // [k][q] bf16
    const short* __restrict__ alignT,   // [b][k][q] bf16                         (PRE=1)
    const float* __restrict__ wind_dirs,
    const float* __restrict__ wind_w,
    const float* __restrict__ wind_b,
    short* __restrict__ outb)
{
  __shared__ short P_s[64 * 76];       // P[q][k], wave-private 16-row slabs

  int bid = blockIdx.x;
  // bid = qt*112 + hh*8 + b  (112%8==0 -> XCD = bid%8 = b)
  int qt  = bid / 112;                 // 0..15
  int rem = bid - qt * 112;
  int hh  = rem >> 3;
  int b   = rem & 7;
  int q0  = qt * 64;
  int kt0 = qt;                        // staggered starting K-tile (order-invariant)

  int t    = threadIdx.x;
  int w    = t >> 6;          // 0..3
  int lane = t & 63;
  int quad = lane >> 4;
  int l16  = lane & 15;

  // Q fragments (A-operand): m = l16 (q row in wave), k = kc*32 + quad*8 + j
  const short* qp = QKV + ((size_t)(b * N_) + q0 + w * 16 + l16) * DQKV_ + hh * DH_;
  bf16x8 qf0 = *(const bf16x8*)(qp + quad * 8);
  bf16x8 qf1 = *(const bf16x8*)(qp + 32 + quad * 8);

  // wind dir trig per q-row -- only needed when align is computed inline
  float cA[4], sA[4];
  if (!PRE){
    #pragma unroll
    for (int rr = 0; rr < 4; rr++){
      float wd = wind_dirs[(size_t)b * N_ + q0 + w * 16 + quad * 4 + rr];
      float A  = wd * 0.017453292519943295f;
      sA[rr] = __sinf(A);
      cA[rr] = __cosf(A);
    }
  }
  // weights pre-scaled by 2*log2e so e^{2z} = exp2(z2) with no extra multiply
  float w0m = wind_w[hh]      * TWO_LOG2E_;
  float w1m = wind_w[H_ + hh] * TWO_LOG2E_;
  float wbm = wind_b[hh]      * TWO_LOG2E_;

  float l[4] = {0.f, 0.f, 0.f, 0.f};
  f32x4 O[4];
  #pragma unroll
  for (int dc = 0; dc < 4; dc++) O[dc] = (f32x4){0.f, 0.f, 0.f, 0.f};

  // global base pointers
  const short* kbase = QKV + (size_t)(b * N_) * DQKV_ + D_ + hh * DH_ + quad * 8;
  const short* vbase = VT + ((size_t)(b * H_ + hh) * DH_) * N_;
  size_t bias_q = (size_t)(q0 + w * 16 + quad * 4);

  for (int it = 0; it < 16; ++it){
    int k0 = ((it + kt0) & 15) * 64;

    // ---- issue all global loads for this tile up front (no barriers anywhere) ----
    bf16x8 kf[4][2];
    #pragma unroll
    for (int jc = 0; jc < 4; jc++){
      const short* kp = kbase + (size_t)(k0 + jc * 16 + l16) * DQKV_;
      kf[jc][0] = *(const bf16x8*)kp;
      kf[jc][1] = *(const bf16x8*)(kp + 32);
    }
    bf16x8 vf[2][4];
    #pragma unroll
    for (int kc = 0; kc < 2; kc++)
      #pragma unroll
      for (int dc = 0; dc < 4; dc++)
        vf[kc][dc] = *(const bf16x8*)(vbase + (size_t)(dc * 16 + l16) * N_ +
                                      k0 + kc * 32 + quad * 8);
    u32x4 cs4a[4]; bf16x4 al4a[4]; bf16x4 av4a[4];
    #pragma unroll
    for (int jc = 0; jc < 4; jc++){
      size_t off = (size_t)(k0 + jc * 16 + l16) * N_ + bias_q;
      if (PRE) al4a[jc] = *(const bf16x4*)(alignT + (size_t)b * N_ * N_ + off);
      else     cs4a[jc] = *(const u32x4*)(csb + off);
      av4a[jc] = *(const bf16x4*)(adjT + off);
    }

    // S = Q K^T  (rows q, cols k) -- already in exp2 domain via Q scale
    f32x4 S[4];
    __builtin_amdgcn_s_setprio(1);
    #pragma unroll
    for (int jc = 0; jc < 4; jc++){
      S[jc] = (f32x4){0.f, 0.f, 0.f, 0.f};
      S[jc] = __builtin_amdgcn_mfma_f32_16x16x32_bf16(qf0, kf[jc][0], S[jc], 0, 0, 0);
      S[jc] = __builtin_amdgcn_mfma_f32_16x16x32_bf16(qf1, kf[jc][1], S[jc], 0, 0, 0);
    }
    __builtin_amdgcn_s_setprio(0);

    // ---- interleaved halves: bias(jc pair) -> PV(kc) ----
    #pragma unroll
    for (int kc = 0; kc < 2; kc++){
      #pragma unroll
      for (int jc = kc * 2; jc < kc * 2 + 2; jc++){
        float ev[4];
        #pragma unroll
        for (int rr = 0; rr < 4; rr++){
          float av = bf2f(av4a[jc][rr]);
          float align;
          if (PRE){
            align = bf2f(al4a[jc][rr]);
          } else {
            unsigned u = cs4a[jc][rr];
            float cB = asf(u << 16);
            float sB = asf(u & 0xffff0000u);
            align = cA[rr] * cB + sA[rr] * sB;
          }
          float z2 = fmaf(align, w0m, fmaf(av, w1m, wbm));    // 2*log2e*z
          float e2 = __builtin_amdgcn_exp2f(z2);              // e^{2z}
          float rc = __builtin_amdgcn_rcpf(e2 + 1.f);
          float bias2 = fmaf(-TWO_LOG2E_, rc, BIAS_C_);       // log2e*(tanh(z) - M0)
          float sv = (av > 0.f ? S[jc][rr] : -1e30f) + bias2;
          float e = __builtin_amdgcn_exp2f(sv);
          l[rr] += e;
          ev[rr] = e;
        }
        unsigned pk01 = cvt_pk_bf16(ev[0], ev[1]);
        unsigned pk23 = cvt_pk_bf16(ev[2], ev[3]);
        short* pb = P_s + (w * 16 + quad * 4) * 76 + jc * 16 + l16;
        pb[0]   = (short)pk01;
        pb[76]  = (short)(pk01 >> 16);
        pb[152] = (short)pk23;
        pb[228] = (short)(pk23 >> 16);
      }

      // PV for this kc half (wave-private P rows; lgkm-ordered, no barrier)
      __builtin_amdgcn_s_setprio(1);
      {
        const short* pp = P_s + (w * 16 + l16) * 76 + kc * 32 + quad * 8;
        bf16x4 p0 = *(const bf16x4*)pp;
        bf16x4 p1 = *(const bf16x4*)(pp + 4);
        bf16x8 pf = { p0[0], p0[1], p0[2], p0[3], p1[0], p1[1], p1[2], p1[3] };
        #pragma unroll
        for (int dc = 0; dc < 4; dc++)
          O[dc] = __builtin_amdgcn_mfma_f32_16x16x32_bf16(pf, vf[kc][dc], O[dc], 0, 0, 0);
      }
      __builtin_amdgcn_s_setprio(0);
    }
  }

  // epilogue: reduce l across the 16 lanes of the row group, O / l, write bf16
  float rl[4];
  #pragma unroll
  for (int rr = 0; rr < 4; rr++){
    float rs = l[rr];
    rs += __shfl_xor(rs, 1);
    rs += __shfl_xor(rs, 2);
    rs += __shfl_xor(rs, 4);
    rs += __shfl_xor(rs, 8);
    rl[rr] = 1.f / rs;
  }
  short* op = outb + ((size_t)(b * N_) + q0 + w * 16) * D_ + hh * DH_;
  #pragma unroll
  for (int rr = 0; rr < 4; rr++)
    #pragma unroll
    for (int dc = 0; dc < 4; dc++)
      op[(size_t)(quad * 4 + rr) * D_ + dc * 16 + l16] = f2bf(O[dc][rr] * rl[rr]);
}

extern "C" void kernel_launch(void* const* d_in, const int* in_sizes, int n_in,
                              void* d_out, int out_size, void* d_ws, size_t ws_size,
                              hipStream_t stream)
{
  const float* nf   = (const float*)d_in[0];
  const float* adj  = (const float*)d_in[1];
  const float* wdir = (const float*)d_in[2];
  const float* brg  = (const float*)d_in[3];
  const float* Wq   = (const float*)d_in[4];
  const float* Wk   = (const float*)d_in[5];
  const float* Wv   = (const float*)d_in[6];
  const float* Wo   = (const float*)d_in[7];
  const float* lng  = (const float*)d_in[8];
  const float* lnb  = (const float*)d_in[9];
  const float* ww   = (const float*)d_in[10];
  const float* wbb  = (const float*)d_in[11];
  float* out = (float*)d_out;

  short* base = (short*)d_ws;
  size_t sh = 0;
  short* xln   = base + sh;  sh += (size_t)M_ * D_;        // reused as attn out
  short* WqkvT = base + sh;  sh += (size_t)DQKV_ * D_;
  short* WoT   = base + sh;  sh += (size_t)D_ * D_;
  short* QKV   = base + sh;  sh += (size_t)M_ * DQKV_;
  short* VT    = base + sh;  sh += (size_t)B_ * H_ * DH_ * N_;       // 14.7 MB
  unsigned* csb = (unsigned*)(base + sh); sh += (size_t)N_ * N_ * 2; // u32 = 2 shorts
  short* adjT  = base + sh;  sh += (size_t)N_ * N_;
  short* alignT = base + sh; sh += (size_t)B_ * N_ * N_;   // optional (pre)
  size_t need_pre = sh * sizeof(short);
  bool pre = (ws_size >= need_pre);

  ln_kernel<<<M_, 256, 0, stream>>>(nf, lng, lnb, xln);
  transpose_kernel<<<dim3(14, 14, 4), 256, 0, stream>>>(Wq, Wk, Wv, Wo, WqkvT, WoT);
  prep_kernel<<<dim3(16, 16), 256, 0, stream>>>(adj, brg, wdir, csb, adjT, alignT, pre ? 1 : 0);
  gemm_bt<<<dim3(M_ / 128, DQKV_ / 128), 256, 0, stream>>>(xln, WqkvT, QKV, nullptr, nullptr, DQKV_, 1);
  vt_kernel<<<dim3(16, 112), 256, 0, stream>>>(QKV, VT);
  if (pre)
    attn_kernel<1><<<B_ * H_ * 16, 256, 0, stream>>>(QKV, VT, csb, adjT, alignT, wdir, ww, wbb, xln);
  else
    attn_kernel<0><<<B_ * H_ * 16, 256, 0, stream>>>(QKV, VT, csb, adjT, alignT, wdir, ww, wbb, xln);
  gemm_bt<<<dim3(M_ / 128, D_ / 128), 256, 0, stream>>>(xln, WoT, nullptr, out, nf, D_, 0);
}